// Round 10
// baseline (551.202 us; speedup 1.0000x reference)
//
#include <hip/hip_runtime.h>
#include <hip/hip_bf16.h>

// Problem dims
#define B_  2
#define C_  256
#define N_  4096
#define R_  8
#define G_  4
#define CG_ 64

typedef __attribute__((ext_vector_type(8))) short short8;
typedef __attribute__((ext_vector_type(4))) float f32x4;

#define MFMA16(a, b, c) __builtin_amdgcn_mfma_f32_16x16x32_bf16((a), (b), (c), 0, 0, 0)
#define EXP2F(x) __builtin_amdgcn_exp2f(x)
#define LOG2E 1.44269504088896f

__device__ inline unsigned int pk2(float a, float b) {
    union { __hip_bfloat162 h; unsigned int u; } cv;
    cv.h = __float22bfloat162_rn(float2{a, b});
    return cv.u;
}
__device__ inline unsigned short f2bf(float f) {
    union { __hip_bfloat16 h; unsigned short u; } cv;
    cv.h = __float2bfloat16(f);
    return cv.u;
}

// Workspace (ushort units unless noted). All hot data in MFMA fragment order
// [tile][lane 64][8 bf16] -> every hot load is a coalesced 1KB dwordx4.
//  qF  [db 4][nt 256][64][8]  (log2e folded; lanes>=16 zero)
//  kF  [db 4][mt 256][64][8]  (lanes>=16 zero)
//  VF  [db 4][ct 16][nc 128][64][8]  V frags (bias applied)
//  l2z f32 [db 4][n 4096] = -log2(Z)
#define QF_OFF   0
#define KF_OFF   524288
#define VF_OFF   1048576
#define L2Z_OFFF 2621440        // float index (byte 10485760)
// total ~10.6 MB

// ---------------------------------------------------------------------------
// Kernel 1: fused proj + grouped conv -> frag-swizzled qF/kF/VF.  (as R8)
// grid(128 n-strips of 32, 1, 4 z=s*2+b), block 256 (4 waves).
// ---------------------------------------------------------------------------
#define XSTR 260   // xsf row stride (floats)
#define VTS  56    // vtmp row stride (shorts)

__global__ __launch_bounds__(256) void fused_pre(
    const float* __restrict__ fL, const float* __restrict__ fU,
    const float* __restrict__ qLw, const float* __restrict__ qLb,
    const float* __restrict__ kLw, const float* __restrict__ kLb,
    const float* __restrict__ vLw, const float* __restrict__ vLb,
    const float* __restrict__ qUw, const float* __restrict__ qUb,
    const float* __restrict__ kUw, const float* __restrict__ kUb,
    const float* __restrict__ vUw, const float* __restrict__ vUb,
    unsigned short* __restrict__ wsu)
{
    const int s   = blockIdx.z >> 1;
    const int b   = blockIdx.z & 1;
    const int nc0 = blockIdx.x;        // 32-n strip index
    const int n0  = nc0 * 32;
    const int t   = threadIdx.x;

    const float* x  = (s ? fU : fL) + (size_t)b * C_ * N_;
    const float* wq = s ? qUw : qLw;
    const float* bq = s ? qUb : qLb;
    const float* wk = s ? kUw : kLw;
    const float* bk = s ? kUb : kLb;
    const float* wv = s ? vUw : vLw;
    const float* bv = s ? vUb : vLb;
    const int dq = s, dk = 1 - s, dv = 1 - s;

    __shared__ __align__(16) float xsf[32 * XSTR];           // [n 32][c 256]
    __shared__ __align__(16) unsigned short vtmp[256 * VTS]; // [c 256][n 32]
    __shared__ __align__(16) float qtmp[2][16][17];

    const int w  = t >> 6;
    const int l  = t & 63;
    const int lm = l & 15;
    const int q  = l >> 4;

    // ---- stage x: dense coalesced reads, transpose into LDS fp32 ----
    {
        const int cr   = w * 8 + (l >> 3);  // c row within 32-chunk
        const int ncl_ = (l & 7) * 4;       // n col
        float4 xv[8];
#pragma unroll
        for (int it = 0; it < 8; it++)
            xv[it] = *reinterpret_cast<const float4*>(
                x + (size_t)(it * 32 + cr) * N_ + n0 + ncl_);
#pragma unroll
        for (int it = 0; it < 8; it++) {
            const int c = it * 32 + cr;
            xsf[(ncl_ + 0) * XSTR + c] = xv[it].x;
            xsf[(ncl_ + 1) * XSTR + c] = xv[it].y;
            xsf[(ncl_ + 2) * XSTR + c] = xv[it].z;
            xsf[(ncl_ + 3) * XSTR + c] = xv[it].w;
        }
    }
    __syncthreads();

    const int ncl = w & 1;
    const int gh  = w >> 1;
    const int nrow = ncl * 16 + lm;

    // ---- B-frags: B[col=n=lm][k=c=kc*32+q*8+j] from xsf (pack fp32->bf16) ----
    short8 bf[8];
    {
        const float* xr = xsf + nrow * XSTR + q * 8;
        const int kclo = (gh == 0) ? 0 : 4;
#pragma unroll
        for (int kc = 0; kc < 8; kc++) {
            if (kc < kclo) continue;
            const float4 f0 = *reinterpret_cast<const float4*>(xr + kc * 32);
            const float4 f1 = *reinterpret_cast<const float4*>(xr + kc * 32 + 4);
            union { unsigned int u[4]; short8 v; } bb;
            bb.u[0] = pk2(f0.x, f0.y); bb.u[1] = pk2(f0.z, f0.w);
            bb.u[2] = pk2(f1.x, f1.y); bb.u[3] = pk2(f1.z, f1.w);
            bf[kc] = bb.v;
        }
    }

    // ---- proj (gh==0 waves): rows 0-7 q (log2e-scaled), 8-15 k ----
    if (gh == 0) {
        const int o = lm;
        const float* wrow = (o < 8) ? (wq + o * C_) : (wk + (o - 8) * C_);
        const float scl = (o < 8) ? LOG2E : 1.0f;
        f32x4 pa = {0.f, 0.f, 0.f, 0.f};
#pragma unroll
        for (int kc = 0; kc < 8; kc++) {
            const float4 w0 = *reinterpret_cast<const float4*>(wrow + kc * 32 + q * 8);
            const float4 w1 = *reinterpret_cast<const float4*>(wrow + kc * 32 + q * 8 + 4);
            union { unsigned int u[4]; short8 v; } aw;
            aw.u[0] = pk2(w0.x * scl, w0.y * scl);
            aw.u[1] = pk2(w0.z * scl, w0.w * scl);
            aw.u[2] = pk2(w1.x * scl, w1.y * scl);
            aw.u[3] = pk2(w1.z * scl, w1.w * scl);
            pa = MFMA16(aw.v, bf[kc], pa);
        }
        // bias, transpose via same-wave LDS bounce, frag-order store
#pragma unroll
        for (int r = 0; r < 4; r++) {
            const int oo = q * 4 + r;
            qtmp[w][oo][lm] = pa[r] + ((q < 2) ? bq[oo] * LOG2E : bk[oo - 8]);
        }
        const int nt = nc0 * 2 + w;      // 16-n tile index
        uint4 pq = {0u, 0u, 0u, 0u}, pk = {0u, 0u, 0u, 0u};
        if (q == 0) {
            float aq[8], ak[8];
#pragma unroll
            for (int o2 = 0; o2 < 8; o2++) { aq[o2] = qtmp[w][o2][lm]; ak[o2] = qtmp[w][8 + o2][lm]; }
            pq.x = pk2(aq[0], aq[1]); pq.y = pk2(aq[2], aq[3]);
            pq.z = pk2(aq[4], aq[5]); pq.w = pk2(aq[6], aq[7]);
            pk.x = pk2(ak[0], ak[1]); pk.y = pk2(ak[2], ak[3]);
            pk.z = pk2(ak[4], ak[5]); pk.w = pk2(ak[6], ak[7]);
        }
        *reinterpret_cast<uint4*>(wsu + QF_OFF + ((size_t)(dq * B_ + b) * 256 + nt) * 512 + l * 8) = pq;
        *reinterpret_cast<uint4*>(wsu + KF_OFF + ((size_t)(dk * B_ + b) * 256 + nt) * 512 + l * 8) = pk;
    }

    // ---- grouped conv: this wave's two groups -> vtmp [c][n] ----
    {
#pragma unroll
        for (int gi = 0; gi < 2; gi++) {
            const int g = gh * 2 + gi;
#pragma unroll
            for (int ocb = 0; ocb < 4; ocb++) {
                f32x4 ca = {0.f, 0.f, 0.f, 0.f};
#pragma unroll
                for (int kc2 = 0; kc2 < 2; kc2++) {
                    const float* wr = wv + (size_t)g * (CG_ * CG_)
                                    + (ocb * 16 + lm) * CG_ + kc2 * 32 + q * 8;
                    const float4 w0 = *reinterpret_cast<const float4*>(wr);
                    const float4 w1 = *reinterpret_cast<const float4*>(wr + 4);
                    union { unsigned int u[4]; short8 v; } aw;
                    aw.u[0] = pk2(w0.x, w0.y); aw.u[1] = pk2(w0.z, w0.w);
                    aw.u[2] = pk2(w1.x, w1.y); aw.u[3] = pk2(w1.z, w1.w);
                    ca = MFMA16(aw.v, bf[g * 2 + kc2], ca);
                }
#pragma unroll
                for (int r = 0; r < 4; r++) {
                    const int c = g * 64 + ocb * 16 + q * 4 + r;
                    vtmp[c * VTS + ncl * 16 + lm] = f2bf(ca[r] + bv[c]);
                }
            }
        }
    }
    __syncthreads();

    // ---- emit VF frags: A[row=c_local=lm][k=n_local=q*8+j], coalesced ----
    {
        const int db = dv * B_ + b;
#pragma unroll
        for (int ctl = 0; ctl < 4; ctl++) {
            const int ct = w * 4 + ctl;
            const uint4 v4 = *reinterpret_cast<const uint4*>(vtmp + (ct * 16 + lm) * VTS + q * 8);
            *reinterpret_cast<uint4*>(
                wsu + VF_OFF + ((size_t)(db * 16 + ct) * 128 + nc0) * 512 + l * 8) = v4;
        }
    }
}

// ---------------------------------------------------------------------------
// Kernel 2: l2z[db][n] = -log2( sum_m exp2(s'[n][m]) ), rank-8 padded MFMA.
// grid(128 n-strips of 32, B, 2), block 256; wave w sums m-quarter.  (as R8)
// ---------------------------------------------------------------------------
__global__ __launch_bounds__(256) void zcalc(const unsigned short* __restrict__ wsu,
                                             float* __restrict__ wsf)
{
    const int d   = blockIdx.z;
    const int b   = blockIdx.y;
    const int nc0 = blockIdx.x;
    const int db  = d * B_ + b;
    const int t   = threadIdx.x;
    const int w   = t >> 6;
    const int l   = t & 63;
    const int lm  = l & 15;
    const int q   = l >> 4;

    const unsigned short* qF = wsu + QF_OFF + (size_t)db * 256 * 512;
    const unsigned short* kF = wsu + KF_OFF + (size_t)db * 256 * 512;

    const short8 qf0 = *reinterpret_cast<const short8*>(qF + (size_t)(nc0 * 2 + 0) * 512 + l * 8);
    const short8 qf1 = *reinterpret_cast<const short8*>(qF + (size_t)(nc0 * 2 + 1) * 512 + l * 8);

    const f32x4 zero = {0.f, 0.f, 0.f, 0.f};
    float za0[4] = {0.f, 0.f, 0.f, 0.f};
    float za1[4] = {0.f, 0.f, 0.f, 0.f};

    short8 kc_ = *reinterpret_cast<const short8*>(kF + (size_t)(w * 64) * 512 + l * 8);
    for (int it = 0; it < 64; it++) {
        const int nmt = w * 64 + ((it + 1) & 63);
        const short8 kn = *reinterpret_cast<const short8*>(kF + (size_t)nmt * 512 + l * 8);
        const f32x4 s0 = MFMA16(qf0, kc_, zero);
        const f32x4 s1 = MFMA16(qf1, kc_, zero);
#pragma unroll
        for (int r = 0; r < 4; r++) { za0[r] += EXP2F(s0[r]); za1[r] += EXP2F(s1[r]); }
        kc_ = kn;
    }

#pragma unroll
    for (int r = 0; r < 4; r++) {
        za0[r] += __shfl_xor(za0[r], 1); za0[r] += __shfl_xor(za0[r], 2);
        za0[r] += __shfl_xor(za0[r], 4); za0[r] += __shfl_xor(za0[r], 8);
        za1[r] += __shfl_xor(za1[r], 1); za1[r] += __shfl_xor(za1[r], 2);
        za1[r] += __shfl_xor(za1[r], 4); za1[r] += __shfl_xor(za1[r], 8);
    }

    __shared__ __align__(16) float zred[4][2][16];
    if (lm == 0) {
        *reinterpret_cast<float4*>(&zred[w][0][q * 4]) = float4{za0[0], za0[1], za0[2], za0[3]};
        *reinterpret_cast<float4*>(&zred[w][1][q * 4]) = float4{za1[0], za1[1], za1[2], za1[3]};
    }
    __syncthreads();
    if (t < 32) {
        const float Z = zred[0][t >> 4][t & 15] + zred[1][t >> 4][t & 15]
                      + zred[2][t >> 4][t & 15] + zred[3][t >> 4][t & 15];
        wsf[L2Z_OFFF + (size_t)db * N_ + nc0 * 32 + t] = -__log2f(Z);
    }
}

// ---------------------------------------------------------------------------
// Kernel 3: out = f + beta * V · E, E computed ONCE per (n,m).
// Block tile 256c x 64m (full C), BK=128 -> 32 ksteps, ONE barrier/kstep.
// 256 blocks, 1 block/CU, __launch_bounds__(256,1) -> 512-VGPR budget for
// full register double-buffering of A (2x16 frags) without spill.
// XCD-pinned: xcd=id&7 -> db=xcd>>1; per-XCD hot set (VF 2MB + q/k 1MB) < 4MB
// L2 -> V re-reads served XCD-locally. A-traffic halves vs M=32 (512 MB).
// Per kstep: wave w E-gens n-slice w*32 over all 64 m (8 padded MFMAs, l2z in
// C-op, 32 exp2) -> barrier -> 16 ds_read_b128 + 64 main MFMAs; next A/q/z
// loads issue post-barrier, drained by the next barrier (full-kstep cover).
// ---------------------------------------------------------------------------
#define ESTR 136   // Es row stride (shorts): 272B rows, 16B-aligned

__global__ __launch_bounds__(256, 1) void attn_gemm(
    const float* __restrict__ fL, const float* __restrict__ fU,
    const float* __restrict__ betap,
    const unsigned short* __restrict__ wsu,
    const float* __restrict__ wsf,
    float* __restrict__ out)
{
    const int id  = blockIdx.x;
    const int xcd = id & 7;
    const int db  = xcd >> 1;
    const int mt  = (id >> 3) + ((xcd & 1) << 5);   // 0..63
    const int d   = db >> 1;
    const int b   = db & 1;
    const int t   = threadIdx.x;
    const int w   = t >> 6;
    const int l   = t & 63;
    const int lm  = l & 15;
    const int q   = l >> 4;
    const int m0  = mt * 64;

    const unsigned short* qF = wsu + QF_OFF + (size_t)db * 256 * 512;
    const unsigned short* kF = wsu + KF_OFF + (size_t)db * 256 * 512;
    const unsigned short* VF = wsu + VF_OFF + (size_t)db * 16 * 128 * 512;
    const float* l2z = wsf + L2Z_OFFF + (size_t)db * N_;
    const float* f = ((d == 0) ? fL : fU) + (size_t)b * C_ * N_;
    float*       o = out + (size_t)db * C_ * N_;

    __shared__ __align__(16) unsigned short Es[2][64 * ESTR];  // [m 64][n 128]

    // persistent k-frags: this block's 64 m (zero quads baked into kF)
    short8 kf2[4];
#pragma unroll
    for (int mb = 0; mb < 4; mb++)
        kf2[mb] = *reinterpret_cast<const short8*>(
            kF + (size_t)(mt * 4 + mb) * 512 + l * 8);

    // A-frag bases: wave w owns c-tiles w*4..w*4+3
    const unsigned short* Ab[4];
#pragma unroll
    for (int cb = 0; cb < 4; cb++)
        Ab[cb] = VF + (size_t)(w * 4 + cb) * 128 * 512 + l * 8;

    f32x4 acc[4][4];
#pragma unroll
    for (int cb = 0; cb < 4; cb++)
#pragma unroll
        for (int mb = 0; mb < 4; mb++) acc[cb][mb] = f32x4{0.f, 0.f, 0.f, 0.f};

    short8 A[2][16];
    short8 qv[2][2];
    f32x4  zv[2][2];

    auto loadA = [&](int buf, int i) {
        const int nc = i * 4;
#pragma unroll
        for (int cb = 0; cb < 4; cb++)
#pragma unroll
            for (int kc = 0; kc < 4; kc++)
                A[buf][cb * 4 + kc] = *reinterpret_cast<const short8*>(
                    Ab[cb] + (size_t)(nc + kc) * 512);
    };
    auto loadQZ = [&](int buf, int i) {
#pragma unroll
        for (int nc = 0; nc < 2; nc++) {
            qv[buf][nc] = *reinterpret_cast<const short8*>(
                qF + (size_t)(i * 8 + w * 2 + nc) * 512 + l * 8);
            zv[buf][nc] = *reinterpret_cast<const f32x4*>(
                l2z + i * 128 + w * 32 + nc * 16 + q * 4);
        }
    };
    // E-gen: wave slice = n cols w*32..+31 over all 64 m
    auto egen = [&](int buf, unsigned short* Eb) {
#pragma unroll
        for (int mb = 0; mb < 4; mb++)
#pragma unroll
            for (int nc = 0; nc < 2; nc++) {
                const f32x4 sv = MFMA16(qv[buf][nc], kf2[mb], zv[buf][nc]);
                uint2 p;
                p.x = pk2(EXP2F(sv[0]), EXP2F(sv[1]));
                p.y = pk2(EXP2F(sv[2]), EXP2F(sv[3]));
                *reinterpret_cast<uint2*>(
                    Eb + (mb * 16 + lm) * ESTR + w * 32 + nc * 16 + q * 4) = p;
            }
    };
    auto mainm = [&](int buf, const unsigned short* Eb) {
#pragma unroll
        for (int kc = 0; kc < 4; kc++) {
            short8 Bf[4];
#pragma unroll
            for (int mb = 0; mb < 4; mb++)
                Bf[mb] = *reinterpret_cast<const short8*>(
                    Eb + (mb * 16 + lm) * ESTR + kc * 32 + q * 8);
#pragma unroll
            for (int cb = 0; cb < 4; cb++)
#pragma unroll
                for (int mb = 0; mb < 4; mb++)
                    acc[cb][mb] = MFMA16(A[buf][cb * 4 + kc], Bf[mb], acc[cb][mb]);
        }
    };

    loadA(0, 0);
    loadQZ(0, 0);

    for (int i = 0; i < 32; i++) {
        const int ib = i & 1;
        unsigned short* Eb = Es[ib];
        egen(ib, Eb);
        __syncthreads();                 // Es ready; drains A/QZ(i) from last iter
        loadA(1 - ib, (i + 1) & 31);     // full-kstep cover before next drain
        loadQZ(1 - ib, (i + 1) & 31);
        mainm(ib, Eb);
    }

    // epilogue: out = f + beta * acc  (D rows c = q*4+r, col m = lm)
    const float beta = *betap;
#pragma unroll
    for (int cb = 0; cb < 4; cb++) {
#pragma unroll
        for (int mb = 0; mb < 4; mb++) {
            const int c = w * 64 + cb * 16 + q * 4;
            const int m = m0 + mb * 16 + lm;
#pragma unroll
            for (int r = 0; r < 4; r++) {
                const size_t off = (size_t)(c + r) * N_ + m;
                o[off] = f[off] + beta * acc[cb][mb][r];
            }
        }
    }
}

// ---------------------------------------------------------------------------
extern "C" void kernel_launch(void* const* d_in, const int* in_sizes, int n_in,
                              void* d_out, int out_size, void* d_ws, size_t ws_size,
                              hipStream_t stream)
{
    const float* fL   = (const float*)d_in[0];
    const float* fU   = (const float*)d_in[1];
    const float* qL_w = (const float*)d_in[2];
    const float* qL_b = (const float*)d_in[3];
    const float* kU_w = (const float*)d_in[4];
    const float* kU_b = (const float*)d_in[5];
    const float* vU_w = (const float*)d_in[6];
    const float* vU_b = (const float*)d_in[7];
    const float* qU_w = (const float*)d_in[8];
    const float* qU_b = (const float*)d_in[9];
    const float* kL_w = (const float*)d_in[10];
    const float* kL_b = (const float*)d_in[11];
    const float* vL_w = (const float*)d_in[12];
    const float* vL_b = (const float*)d_in[13];
    const float* beta = (const float*)d_in[14];

    unsigned short* wsu  = (unsigned short*)d_ws;
    float*          wsf  = (float*)d_ws;
    float*          outf = (float*)d_out;

    fused_pre<<<dim3(128, 1, 4), 256, 0, stream>>>(
        fL, fU, qL_w, qL_b, kL_w, kL_b, vL_w, vL_b,
        qU_w, qU_b, kU_w, kU_b, vU_w, vU_b, wsu);

    zcalc<<<dim3(128, B_, 2), 256, 0, stream>>>(wsu, wsf);

    attn_gemm<<<dim3(256), 256, 0, stream>>>(
        fL, fU, beta, wsu, wsf, outf);
}

// Round 11
// 384.275 us; speedup vs baseline: 1.4344x; 1.4344x over previous
//
#include <hip/hip_runtime.h>
#include <hip/hip_bf16.h>

// Problem dims
#define B_  2
#define C_  256
#define N_  4096
#define R_  8
#define G_  4
#define CG_ 64

typedef __attribute__((ext_vector_type(8))) short short8;
typedef __attribute__((ext_vector_type(4))) float f32x4;

#define MFMA16(a, b, c) __builtin_amdgcn_mfma_f32_16x16x32_bf16((a), (b), (c), 0, 0, 0)
#define EXP2F(x) __builtin_amdgcn_exp2f(x)
#define LOG2E 1.44269504088896f

__device__ inline unsigned int pk2(float a, float b) {
    union { __hip_bfloat162 h; unsigned int u; } cv;
    cv.h = __float22bfloat162_rn(float2{a, b});
    return cv.u;
}
__device__ inline unsigned short f2bf(float f) {
    union { __hip_bfloat16 h; unsigned short u; } cv;
    cv.h = __float2bfloat16(f);
    return cv.u;
}

// Workspace (ushort units unless noted). All hot data in MFMA fragment order
// [tile][lane 64][8 bf16] -> every hot load is a coalesced 1KB dwordx4.
//  qF  [db 4][nt 256][64][8]  (log2e folded; lanes>=16 zero)
//  kF  [db 4][mt 256][64][8]  (lanes>=16 zero)
//  VF  [db 4][ct 16][nc 128][64][8]  V frags (bias applied)
//  l2z f32 [db 4][n 4096] = -log2(Z)
#define QF_OFF   0
#define KF_OFF   524288
#define VF_OFF   1048576
#define L2Z_OFFF 2621440        // float index (byte 10485760)
// total ~10.6 MB

// ---------------------------------------------------------------------------
// Kernel 1: fused proj + grouped conv -> frag-swizzled qF/kF/VF.
// Weights staged COALESCED into LDS once per block (padded strides -> 2-way
// free frag reads); xsf region reused for vtmp. Coalesced x reads as R8.
// grid(128 n-strips of 32, 1, 4 z=s*2+b), block 256 (4 waves).
// LDS: xsf 33280 + wqks 8448 + wvs 36864 + qtmp 2176 = 80768 B -> 2 blocks/CU.
// ---------------------------------------------------------------------------
#define XSTR 260   // xsf row stride (floats)
#define VTS  56    // vtmp row stride (shorts), vtmp aliases xsf region
#define WQS  264   // wqks row stride (shorts): 132 dw == 4 mod 32 -> 2-way
#define WVS  72    // wvs row stride (shorts): 36 dw == 4 mod 32 -> 2-way

__global__ __launch_bounds__(256) void fused_pre(
    const float* __restrict__ fL, const float* __restrict__ fU,
    const float* __restrict__ qLw, const float* __restrict__ qLb,
    const float* __restrict__ kLw, const float* __restrict__ kLb,
    const float* __restrict__ vLw, const float* __restrict__ vLb,
    const float* __restrict__ qUw, const float* __restrict__ qUb,
    const float* __restrict__ kUw, const float* __restrict__ kUb,
    const float* __restrict__ vUw, const float* __restrict__ vUb,
    unsigned short* __restrict__ wsu)
{
    const int s   = blockIdx.z >> 1;
    const int b   = blockIdx.z & 1;
    const int nc0 = blockIdx.x;        // 32-n strip index
    const int n0  = nc0 * 32;
    const int t   = threadIdx.x;

    const float* x  = (s ? fU : fL) + (size_t)b * C_ * N_;
    const float* wq = s ? qUw : qLw;
    const float* bq = s ? qUb : qLb;
    const float* wk = s ? kUw : kLw;
    const float* bk = s ? kUb : kLb;
    const float* wv = s ? vUw : vLw;
    const float* bv = s ? vUb : vLb;
    const int dq = s, dk = 1 - s, dv = 1 - s;

    __shared__ __align__(16) float xsf[32 * XSTR];            // 33280 B, reused as vtmp
    __shared__ __align__(16) unsigned short wqks[16 * WQS];   // 8448 B
    __shared__ __align__(16) unsigned short wvs[256 * WVS];   // 36864 B
    __shared__ __align__(16) float qtmp[2][16][17];           // 2176 B

    unsigned short* vtmp = reinterpret_cast<unsigned short*>(xsf);

    const int w  = t >> 6;
    const int l  = t & 63;
    const int lm = l & 15;
    const int q  = l >> 4;

    // ---- stage weights into LDS, coalesced (bf16, q rows pre-scaled) ----
    for (int i = t; i < 1024; i += 256) {          // wqk: 1024 float4s
        const int o = i >> 6;
        const int c = (i & 63) * 4;
        const float4 w4 = *reinterpret_cast<const float4*>(
            ((o < 8) ? wq + o * C_ : wk + (o - 8) * C_) + c);
        const float scl = (o < 8) ? LOG2E : 1.0f;
        unsigned int* dst = reinterpret_cast<unsigned int*>(wqks + o * WQS + c);
        dst[0] = pk2(w4.x * scl, w4.y * scl);
        dst[1] = pk2(w4.z * scl, w4.w * scl);
    }
    for (int i = t; i < 4096; i += 256) {          // wv: 4096 float4s
        const int row = i >> 4;                    // g*64 + oc
        const int ic  = (i & 15) * 4;
        const float4 w4 = *reinterpret_cast<const float4*>(wv + row * 64 + ic);
        unsigned int* dst = reinterpret_cast<unsigned int*>(wvs + row * WVS + ic);
        dst[0] = pk2(w4.x, w4.y);
        dst[1] = pk2(w4.z, w4.w);
    }

    // ---- stage x: dense coalesced reads, transpose into LDS fp32 ----
    {
        const int cr   = w * 8 + (l >> 3);  // c row within 32-chunk
        const int ncl_ = (l & 7) * 4;       // n col
        float4 xv[8];
#pragma unroll
        for (int it = 0; it < 8; it++)
            xv[it] = *reinterpret_cast<const float4*>(
                x + (size_t)(it * 32 + cr) * N_ + n0 + ncl_);
#pragma unroll
        for (int it = 0; it < 8; it++) {
            const int c = it * 32 + cr;
            xsf[(ncl_ + 0) * XSTR + c] = xv[it].x;
            xsf[(ncl_ + 1) * XSTR + c] = xv[it].y;
            xsf[(ncl_ + 2) * XSTR + c] = xv[it].z;
            xsf[(ncl_ + 3) * XSTR + c] = xv[it].w;
        }
    }
    __syncthreads();

    const int ncl = w & 1;
    const int gh  = w >> 1;
    const int nrow = ncl * 16 + lm;

    // ---- B-frags: B[col=n=lm][k=c=kc*32+q*8+j] from xsf (pack fp32->bf16) ----
    short8 bf[8];
    {
        const float* xr = xsf + nrow * XSTR + q * 8;
        const int kclo = (gh == 0) ? 0 : 4;
#pragma unroll
        for (int kc = 0; kc < 8; kc++) {
            if (kc < kclo) continue;
            const float4 f0 = *reinterpret_cast<const float4*>(xr + kc * 32);
            const float4 f1 = *reinterpret_cast<const float4*>(xr + kc * 32 + 4);
            union { unsigned int u[4]; short8 v; } bb;
            bb.u[0] = pk2(f0.x, f0.y); bb.u[1] = pk2(f0.z, f0.w);
            bb.u[2] = pk2(f1.x, f1.y); bb.u[3] = pk2(f1.z, f1.w);
            bf[kc] = bb.v;
        }
    }
    __syncthreads();   // all xsf reads done -> region reusable as vtmp

    // ---- proj (gh==0 waves): rows 0-7 q (log2e-scaled), 8-15 k ----
    if (gh == 0) {
        f32x4 pa = {0.f, 0.f, 0.f, 0.f};
#pragma unroll
        for (int kc = 0; kc < 8; kc++) {
            const short8 af = *reinterpret_cast<const short8*>(
                wqks + lm * WQS + kc * 32 + q * 8);
            pa = MFMA16(af, bf[kc], pa);
        }
        // bias, transpose via same-wave LDS bounce, frag-order store
#pragma unroll
        for (int r = 0; r < 4; r++) {
            const int oo = q * 4 + r;
            qtmp[w][oo][lm] = pa[r] + ((q < 2) ? bq[oo] * LOG2E : bk[oo - 8]);
        }
        const int nt = nc0 * 2 + w;      // 16-n tile index
        uint4 pq = {0u, 0u, 0u, 0u}, pk = {0u, 0u, 0u, 0u};
        if (q == 0) {
            float aq[8], ak[8];
#pragma unroll
            for (int o2 = 0; o2 < 8; o2++) { aq[o2] = qtmp[w][o2][lm]; ak[o2] = qtmp[w][8 + o2][lm]; }
            pq.x = pk2(aq[0], aq[1]); pq.y = pk2(aq[2], aq[3]);
            pq.z = pk2(aq[4], aq[5]); pq.w = pk2(aq[6], aq[7]);
            pk.x = pk2(ak[0], ak[1]); pk.y = pk2(ak[2], ak[3]);
            pk.z = pk2(ak[4], ak[5]); pk.w = pk2(ak[6], ak[7]);
        }
        *reinterpret_cast<uint4*>(wsu + QF_OFF + ((size_t)(dq * B_ + b) * 256 + nt) * 512 + l * 8) = pq;
        *reinterpret_cast<uint4*>(wsu + KF_OFF + ((size_t)(dk * B_ + b) * 256 + nt) * 512 + l * 8) = pk;
    }

    // ---- grouped conv: this wave's two groups -> vtmp [c][n] ----
    {
#pragma unroll
        for (int gi = 0; gi < 2; gi++) {
            const int g = gh * 2 + gi;
#pragma unroll
            for (int ocb = 0; ocb < 4; ocb++) {
                f32x4 ca = {0.f, 0.f, 0.f, 0.f};
#pragma unroll
                for (int kc2 = 0; kc2 < 2; kc2++) {
                    const short8 af = *reinterpret_cast<const short8*>(
                        wvs + (g * 64 + ocb * 16 + lm) * WVS + kc2 * 32 + q * 8);
                    ca = MFMA16(af, bf[g * 2 + kc2], ca);
                }
#pragma unroll
                for (int r = 0; r < 4; r++) {
                    const int c = g * 64 + ocb * 16 + q * 4 + r;
                    vtmp[c * VTS + ncl * 16 + lm] = f2bf(ca[r] + bv[c]);
                }
            }
        }
    }
    __syncthreads();

    // ---- emit VF frags: A[row=c_local=lm][k=n_local=q*8+j], coalesced ----
    {
        const int db = dv * B_ + b;
#pragma unroll
        for (int ctl = 0; ctl < 4; ctl++) {
            const int ct = w * 4 + ctl;
            const uint4 v4 = *reinterpret_cast<const uint4*>(vtmp + (ct * 16 + lm) * VTS + q * 8);
            *reinterpret_cast<uint4*>(
                wsu + VF_OFF + ((size_t)(db * 16 + ct) * 128 + nc0) * 512 + l * 8) = v4;
        }
    }
}

// ---------------------------------------------------------------------------
// Kernel 2: l2z[db][n] = -log2( sum_m exp2(s'[n][m]) ), rank-8 padded MFMA.
// grid(128 n-strips of 32, B, 2), block 256; wave w sums m-quarter.  (as R8)
// ---------------------------------------------------------------------------
__global__ __launch_bounds__(256) void zcalc(const unsigned short* __restrict__ wsu,
                                             float* __restrict__ wsf)
{
    const int d   = blockIdx.z;
    const int b   = blockIdx.y;
    const int nc0 = blockIdx.x;
    const int db  = d * B_ + b;
    const int t   = threadIdx.x;
    const int w   = t >> 6;
    const int l   = t & 63;
    const int lm  = l & 15;
    const int q   = l >> 4;

    const unsigned short* qF = wsu + QF_OFF + (size_t)db * 256 * 512;
    const unsigned short* kF = wsu + KF_OFF + (size_t)db * 256 * 512;

    const short8 qf0 = *reinterpret_cast<const short8*>(qF + (size_t)(nc0 * 2 + 0) * 512 + l * 8);
    const short8 qf1 = *reinterpret_cast<const short8*>(qF + (size_t)(nc0 * 2 + 1) * 512 + l * 8);

    const f32x4 zero = {0.f, 0.f, 0.f, 0.f};
    float za0[4] = {0.f, 0.f, 0.f, 0.f};
    float za1[4] = {0.f, 0.f, 0.f, 0.f};

    short8 kc_ = *reinterpret_cast<const short8*>(kF + (size_t)(w * 64) * 512 + l * 8);
    for (int it = 0; it < 64; it++) {
        const int nmt = w * 64 + ((it + 1) & 63);
        const short8 kn = *reinterpret_cast<const short8*>(kF + (size_t)nmt * 512 + l * 8);
        const f32x4 s0 = MFMA16(qf0, kc_, zero);
        const f32x4 s1 = MFMA16(qf1, kc_, zero);
#pragma unroll
        for (int r = 0; r < 4; r++) { za0[r] += EXP2F(s0[r]); za1[r] += EXP2F(s1[r]); }
        kc_ = kn;
    }

#pragma unroll
    for (int r = 0; r < 4; r++) {
        za0[r] += __shfl_xor(za0[r], 1); za0[r] += __shfl_xor(za0[r], 2);
        za0[r] += __shfl_xor(za0[r], 4); za0[r] += __shfl_xor(za0[r], 8);
        za1[r] += __shfl_xor(za1[r], 1); za1[r] += __shfl_xor(za1[r], 2);
        za1[r] += __shfl_xor(za1[r], 4); za1[r] += __shfl_xor(za1[r], 8);
    }

    __shared__ __align__(16) float zred[4][2][16];
    if (lm == 0) {
        *reinterpret_cast<float4*>(&zred[w][0][q * 4]) = float4{za0[0], za0[1], za0[2], za0[3]};
        *reinterpret_cast<float4*>(&zred[w][1][q * 4]) = float4{za1[0], za1[1], za1[2], za1[3]};
    }
    __syncthreads();
    if (t < 32) {
        const float Z = zred[0][t >> 4][t & 15] + zred[1][t >> 4][t & 15]
                      + zred[2][t >> 4][t & 15] + zred[3][t >> 4][t & 15];
        wsf[L2Z_OFFF + (size_t)db * N_ + nc0 * 32 + t] = -__log2f(Z);
    }
}

// ---------------------------------------------------------------------------
// Kernel 3: out = f + beta * V · E, E computed ONCE per (n,m).
// Block tile 256c x 64m (full C), BK=128 -> 32 ksteps, ONE barrier/kstep.
// 256 blocks x 512 threads (8 waves): wave w owns 32c x 64m -> acc 32 VGPR,
// A-dbuf 32, kf 16, q/z 16 -> ~130 VGPR, NO spill (__launch_bounds__(512,2)).
// 8 waves/CU latency hiding (R10's 1-blk/CU + spill regression fixed).
// XCD-pinned: xcd=id&7 -> db=xcd>>1; per-XCD hot set ~3MB < 4MB L2.
// A-traffic 512MB (half of R8). R8-proven schedule: egen -> barrier ->
// loadA/QZ(next) -> mainm; A has full-kstep cover before its drain.
// ---------------------------------------------------------------------------
#define ESTR 136   // Es row stride (shorts): 68 dw == 4 mod 32 -> 2-way free

__global__ __launch_bounds__(512, 2) void attn_gemm(
    const float* __restrict__ fL, const float* __restrict__ fU,
    const float* __restrict__ betap,
    const unsigned short* __restrict__ wsu,
    const float* __restrict__ wsf,
    float* __restrict__ out)
{
    const int id  = blockIdx.x;
    const int xcd = id & 7;
    const int db  = xcd >> 1;
    const int mt  = (id >> 3) + ((xcd & 1) << 5);   // 0..63
    const int d   = db >> 1;
    const int b   = db & 1;
    const int t   = threadIdx.x;
    const int w   = t >> 6;          // 0..7
    const int l   = t & 63;
    const int lm  = l & 15;
    const int q   = l >> 4;
    const int m0  = mt * 64;

    const unsigned short* qF = wsu + QF_OFF + (size_t)db * 256 * 512;
    const unsigned short* kF = wsu + KF_OFF + (size_t)db * 256 * 512;
    const unsigned short* VF = wsu + VF_OFF + (size_t)db * 16 * 128 * 512;
    const float* l2z = wsf + L2Z_OFFF + (size_t)db * N_;
    const float* f = ((d == 0) ? fL : fU) + (size_t)b * C_ * N_;
    float*       o = out + (size_t)db * C_ * N_;

    __shared__ __align__(16) unsigned short Es[2][64 * ESTR];  // [m 64][n 128]

    // persistent k-frags: this block's 64 m (zero quads baked into kF)
    short8 kf2[4];
#pragma unroll
    for (int mb = 0; mb < 4; mb++)
        kf2[mb] = *reinterpret_cast<const short8*>(
            kF + (size_t)(mt * 4 + mb) * 512 + l * 8);

    // A-frag bases: wave w owns c-tiles w*2, w*2+1 (32 c)
    const unsigned short* Ab[2];
#pragma unroll
    for (int cb = 0; cb < 2; cb++)
        Ab[cb] = VF + (size_t)(w * 2 + cb) * 128 * 512 + l * 8;

    f32x4 acc[2][4];
#pragma unroll
    for (int cb = 0; cb < 2; cb++)
#pragma unroll
        for (int mb = 0; mb < 4; mb++) acc[cb][mb] = f32x4{0.f, 0.f, 0.f, 0.f};

    short8 A[2][8];        // dbuf: 2 c-tiles x 4 kc
    short8 qv[2];
    f32x4  zv[2];

    auto loadA = [&](int buf, int i) {
        const int nc = (i & 31) * 4;
#pragma unroll
        for (int cb = 0; cb < 2; cb++)
#pragma unroll
            for (int kc = 0; kc < 4; kc++)
                A[buf][cb * 4 + kc] = *reinterpret_cast<const short8*>(
                    Ab[cb] + (size_t)(nc + kc) * 512);
    };
    auto loadQZ = [&](int buf, int i) {
        const int ii = i & 31;
        qv[buf] = *reinterpret_cast<const short8*>(
            qF + (size_t)(ii * 8 + w) * 512 + l * 8);
        zv[buf] = *reinterpret_cast<const f32x4*>(
            l2z + ii * 128 + w * 16 + q * 4);
    };
    // E-gen: wave w covers n-slice w*16..+15 over all 64 m
    auto egen = [&](int buf, unsigned short* Eb) {
#pragma unroll
        for (int mb = 0; mb < 4; mb++) {
            const f32x4 sv = MFMA16(qv[buf], kf2[mb], zv[buf]);
            uint2 p;
            p.x = pk2(EXP2F(sv[0]), EXP2F(sv[1]));
            p.y = pk2(EXP2F(sv[2]), EXP2F(sv[3]));
            *reinterpret_cast<uint2*>(
                Eb + (mb * 16 + lm) * ESTR + w * 16 + q * 4) = p;
        }
    };
    auto mainm = [&](int buf, const unsigned short* Eb) {
#pragma unroll
        for (int kc = 0; kc < 4; kc++) {
            short8 Bf[4];
#pragma unroll
            for (int mb = 0; mb < 4; mb++)
                Bf[mb] = *reinterpret_cast<const short8*>(
                    Eb + (mb * 16 + lm) * ESTR + kc * 32 + q * 8);
#pragma unroll
            for (int cb = 0; cb < 2; cb++)
#pragma unroll
                for (int mb = 0; mb < 4; mb++)
                    acc[cb][mb] = MFMA16(A[buf][cb * 4 + kc], Bf[mb], acc[cb][mb]);
        }
    };

    loadA(0, 0);
    loadQZ(0, 0);

    for (int i = 0; i < 32; i++) {
        const int ib = i & 1;
        unsigned short* Eb = Es[ib];
        egen(ib, Eb);
        __syncthreads();                 // Es ready; drains A/QZ(i) from last iter
        loadA(1 - ib, (i + 1) & 31);     // full-kstep cover before next drain
        loadQZ(1 - ib, (i + 1) & 31);
        mainm(ib, Eb);
    }

    // epilogue: out = f + beta * acc  (D rows c = q*4+r, col m = lm)
    const float beta = *betap;
#pragma unroll
    for (int cb = 0; cb < 2; cb++) {
#pragma unroll
        for (int mb = 0; mb < 4; mb++) {
            const int c = w * 32 + cb * 16 + q * 4;
            const int m = m0 + mb * 16 + lm;
#pragma unroll
            for (int r = 0; r < 4; r++) {
                const size_t off = (size_t)(c + r) * N_ + m;
                o[off] = f[off] + beta * acc[cb][mb][r];
            }
        }
    }
}

// ---------------------------------------------------------------------------
extern "C" void kernel_launch(void* const* d_in, const int* in_sizes, int n_in,
                              void* d_out, int out_size, void* d_ws, size_t ws_size,
                              hipStream_t stream)
{
    const float* fL   = (const float*)d_in[0];
    const float* fU   = (const float*)d_in[1];
    const float* qL_w = (const float*)d_in[2];
    const float* qL_b = (const float*)d_in[3];
    const float* kU_w = (const float*)d_in[4];
    const float* kU_b = (const float*)d_in[5];
    const float* vU_w = (const float*)d_in[6];
    const float* vU_b = (const float*)d_in[7];
    const float* qU_w = (const float*)d_in[8];
    const float* qU_b = (const float*)d_in[9];
    const float* kL_w = (const float*)d_in[10];
    const float* kL_b = (const float*)d_in[11];
    const float* vL_w = (const float*)d_in[12];
    const float* vL_b = (const float*)d_in[13];
    const float* beta = (const float*)d_in[14];

    unsigned short* wsu  = (unsigned short*)d_ws;
    float*          wsf  = (float*)d_ws;
    float*          outf = (float*)d_out;

    fused_pre<<<dim3(128, 1, 4), 256, 0, stream>>>(
        fL, fU, qL_w, qL_b, kL_w, kL_b, vL_w, vL_b,
        qU_w, qU_b, kU_w, kU_b, vU_w, vU_b, wsu);

    zcalc<<<dim3(128, B_, 2), 256, 0, stream>>>(wsu, wsf);

    attn_gemm<<<dim3(256), 512, 0, stream>>>(
        fL, fU, beta, wsu, wsf, outf);
}

// Round 12
// 179.955 us; speedup vs baseline: 3.0630x; 2.1354x over previous
//
#include <hip/hip_runtime.h>
#include <hip/hip_bf16.h>

// Problem dims
#define B_  2
#define C_  256
#define N_  4096
#define R_  8
#define G_  4
#define CG_ 64

typedef __attribute__((ext_vector_type(8))) short short8;
typedef __attribute__((ext_vector_type(4))) float f32x4;

#define MFMA16(a, b, c) __builtin_amdgcn_mfma_f32_16x16x32_bf16((a), (b), (c), 0, 0, 0)
#define EXP2F(x) __builtin_amdgcn_exp2f(x)
#define LOG2E 1.44269504088896f

__device__ inline unsigned int pk2(float a, float b) {
    union { __hip_bfloat162 h; unsigned int u; } cv;
    cv.h = __float22bfloat162_rn(float2{a, b});
    return cv.u;
}
__device__ inline unsigned short f2bf(float f) {
    union { __hip_bfloat16 h; unsigned short u; } cv;
    cv.h = __float2bfloat16(f);
    return cv.u;
}

// Workspace (ushort units unless noted). All hot data in MFMA fragment order
// [tile][lane 64][8 bf16] -> every hot load is a coalesced 1KB dwordx4.
//  qF  [db 4][nt 256][64][8]  (log2e folded; lanes>=16 zero)
//  kF  [db 4][mt 256][64][8]  (lanes>=16 zero)
//  VF  [db 4][ct 16][nc 128][64][8]  V frags (bias applied)
//  l2z f32 [db 4][n 4096] = -log2(Z)
#define QF_OFF   0
#define KF_OFF   524288
#define VF_OFF   1048576
#define L2Z_OFFF 2621440        // float index (byte 10485760)
// total ~10.6 MB

// ---------------------------------------------------------------------------
// Kernel 1: fused proj + grouped conv -> frag-swizzled qF/kF/VF.  (as R11)
// Weights staged COALESCED into LDS once per block; xsf reused for vtmp.
// grid(128 n-strips of 32, 1, 4 z=s*2+b), block 256 (4 waves).
// ---------------------------------------------------------------------------
#define XSTR 260   // xsf row stride (floats)
#define VTS  56    // vtmp row stride (shorts), vtmp aliases xsf region
#define WQS  264   // wqks row stride (shorts)
#define WVS  72    // wvs row stride (shorts)

__global__ __launch_bounds__(256) void fused_pre(
    const float* __restrict__ fL, const float* __restrict__ fU,
    const float* __restrict__ qLw, const float* __restrict__ qLb,
    const float* __restrict__ kLw, const float* __restrict__ kLb,
    const float* __restrict__ vLw, const float* __restrict__ vLb,
    const float* __restrict__ qUw, const float* __restrict__ qUb,
    const float* __restrict__ kUw, const float* __restrict__ kUb,
    const float* __restrict__ vUw, const float* __restrict__ vUb,
    unsigned short* __restrict__ wsu)
{
    const int s   = blockIdx.z >> 1;
    const int b   = blockIdx.z & 1;
    const int nc0 = blockIdx.x;        // 32-n strip index
    const int n0  = nc0 * 32;
    const int t   = threadIdx.x;

    const float* x  = (s ? fU : fL) + (size_t)b * C_ * N_;
    const float* wq = s ? qUw : qLw;
    const float* bq = s ? qUb : qLb;
    const float* wk = s ? kUw : kLw;
    const float* bk = s ? kUb : kLb;
    const float* wv = s ? vUw : vLw;
    const float* bv = s ? vUb : vLb;
    const int dq = s, dk = 1 - s, dv = 1 - s;

    __shared__ __align__(16) float xsf[32 * XSTR];            // 33280 B, reused as vtmp
    __shared__ __align__(16) unsigned short wqks[16 * WQS];   // 8448 B
    __shared__ __align__(16) unsigned short wvs[256 * WVS];   // 36864 B
    __shared__ __align__(16) float qtmp[2][16][17];           // 2176 B

    unsigned short* vtmp = reinterpret_cast<unsigned short*>(xsf);

    const int w  = t >> 6;
    const int l  = t & 63;
    const int lm = l & 15;
    const int q  = l >> 4;

    // ---- stage weights into LDS, coalesced (bf16, q rows pre-scaled) ----
    for (int i = t; i < 1024; i += 256) {          // wqk: 1024 float4s
        const int o = i >> 6;
        const int c = (i & 63) * 4;
        const float4 w4 = *reinterpret_cast<const float4*>(
            ((o < 8) ? wq + o * C_ : wk + (o - 8) * C_) + c);
        const float scl = (o < 8) ? LOG2E : 1.0f;
        unsigned int* dst = reinterpret_cast<unsigned int*>(wqks + o * WQS + c);
        dst[0] = pk2(w4.x * scl, w4.y * scl);
        dst[1] = pk2(w4.z * scl, w4.w * scl);
    }
    for (int i = t; i < 4096; i += 256) {          // wv: 4096 float4s
        const int row = i >> 4;                    // g*64 + oc
        const int ic  = (i & 15) * 4;
        const float4 w4 = *reinterpret_cast<const float4*>(wv + row * 64 + ic);
        unsigned int* dst = reinterpret_cast<unsigned int*>(wvs + row * WVS + ic);
        dst[0] = pk2(w4.x, w4.y);
        dst[1] = pk2(w4.z, w4.w);
    }

    // ---- stage x: dense coalesced reads, transpose into LDS fp32 ----
    {
        const int cr   = w * 8 + (l >> 3);  // c row within 32-chunk
        const int ncl_ = (l & 7) * 4;       // n col
        float4 xv[8];
#pragma unroll
        for (int it = 0; it < 8; it++)
            xv[it] = *reinterpret_cast<const float4*>(
                x + (size_t)(it * 32 + cr) * N_ + n0 + ncl_);
#pragma unroll
        for (int it = 0; it < 8; it++) {
            const int c = it * 32 + cr;
            xsf[(ncl_ + 0) * XSTR + c] = xv[it].x;
            xsf[(ncl_ + 1) * XSTR + c] = xv[it].y;
            xsf[(ncl_ + 2) * XSTR + c] = xv[it].z;
            xsf[(ncl_ + 3) * XSTR + c] = xv[it].w;
        }
    }
    __syncthreads();

    const int ncl = w & 1;
    const int gh  = w >> 1;
    const int nrow = ncl * 16 + lm;

    // ---- B-frags: B[col=n=lm][k=c=kc*32+q*8+j] from xsf (pack fp32->bf16) ----
    short8 bf[8];
    {
        const float* xr = xsf + nrow * XSTR + q * 8;
        const int kclo = (gh == 0) ? 0 : 4;
#pragma unroll
        for (int kc = 0; kc < 8; kc++) {
            if (kc < kclo) continue;
            const float4 f0 = *reinterpret_cast<const float4*>(xr + kc * 32);
            const float4 f1 = *reinterpret_cast<const float4*>(xr + kc * 32 + 4);
            union { unsigned int u[4]; short8 v; } bb;
            bb.u[0] = pk2(f0.x, f0.y); bb.u[1] = pk2(f0.z, f0.w);
            bb.u[2] = pk2(f1.x, f1.y); bb.u[3] = pk2(f1.z, f1.w);
            bf[kc] = bb.v;
        }
    }
    __syncthreads();   // all xsf reads done -> region reusable as vtmp

    // ---- proj (gh==0 waves): rows 0-7 q (log2e-scaled), 8-15 k ----
    if (gh == 0) {
        f32x4 pa = {0.f, 0.f, 0.f, 0.f};
#pragma unroll
        for (int kc = 0; kc < 8; kc++) {
            const short8 af = *reinterpret_cast<const short8*>(
                wqks + lm * WQS + kc * 32 + q * 8);
            pa = MFMA16(af, bf[kc], pa);
        }
        // bias, transpose via same-wave LDS bounce, frag-order store
#pragma unroll
        for (int r = 0; r < 4; r++) {
            const int oo = q * 4 + r;
            qtmp[w][oo][lm] = pa[r] + ((q < 2) ? bq[oo] * LOG2E : bk[oo - 8]);
        }
        const int nt = nc0 * 2 + w;      // 16-n tile index
        uint4 pq = {0u, 0u, 0u, 0u}, pk = {0u, 0u, 0u, 0u};
        if (q == 0) {
            float aq[8], ak[8];
#pragma unroll
            for (int o2 = 0; o2 < 8; o2++) { aq[o2] = qtmp[w][o2][lm]; ak[o2] = qtmp[w][8 + o2][lm]; }
            pq.x = pk2(aq[0], aq[1]); pq.y = pk2(aq[2], aq[3]);
            pq.z = pk2(aq[4], aq[5]); pq.w = pk2(aq[6], aq[7]);
            pk.x = pk2(ak[0], ak[1]); pk.y = pk2(ak[2], ak[3]);
            pk.z = pk2(ak[4], ak[5]); pk.w = pk2(ak[6], ak[7]);
        }
        *reinterpret_cast<uint4*>(wsu + QF_OFF + ((size_t)(dq * B_ + b) * 256 + nt) * 512 + l * 8) = pq;
        *reinterpret_cast<uint4*>(wsu + KF_OFF + ((size_t)(dk * B_ + b) * 256 + nt) * 512 + l * 8) = pk;
    }

    // ---- grouped conv: this wave's two groups -> vtmp [c][n] ----
    {
#pragma unroll
        for (int gi = 0; gi < 2; gi++) {
            const int g = gh * 2 + gi;
#pragma unroll
            for (int ocb = 0; ocb < 4; ocb++) {
                f32x4 ca = {0.f, 0.f, 0.f, 0.f};
#pragma unroll
                for (int kc2 = 0; kc2 < 2; kc2++) {
                    const short8 af = *reinterpret_cast<const short8*>(
                        wvs + (g * 64 + ocb * 16 + lm) * WVS + kc2 * 32 + q * 8);
                    ca = MFMA16(af, bf[g * 2 + kc2], ca);
                }
#pragma unroll
                for (int r = 0; r < 4; r++) {
                    const int c = g * 64 + ocb * 16 + q * 4 + r;
                    vtmp[c * VTS + ncl * 16 + lm] = f2bf(ca[r] + bv[c]);
                }
            }
        }
    }
    __syncthreads();

    // ---- emit VF frags: A[row=c_local=lm][k=n_local=q*8+j], coalesced ----
    {
        const int db = dv * B_ + b;
#pragma unroll
        for (int ctl = 0; ctl < 4; ctl++) {
            const int ct = w * 4 + ctl;
            const uint4 v4 = *reinterpret_cast<const uint4*>(vtmp + (ct * 16 + lm) * VTS + q * 8);
            *reinterpret_cast<uint4*>(
                wsu + VF_OFF + ((size_t)(db * 16 + ct) * 128 + nc0) * 512 + l * 8) = v4;
        }
    }
}

// ---------------------------------------------------------------------------
// Kernel 2: l2z[db][n] = -log2( sum_m exp2(s'[n][m]) ), rank-8 padded MFMA.
// grid(128 n-strips of 32, B, 2), block 256; wave w sums m-quarter.  (as R8)
// ---------------------------------------------------------------------------
__global__ __launch_bounds__(256) void zcalc(const unsigned short* __restrict__ wsu,
                                             float* __restrict__ wsf)
{
    const int d   = blockIdx.z;
    const int b   = blockIdx.y;
    const int nc0 = blockIdx.x;
    const int db  = d * B_ + b;
    const int t   = threadIdx.x;
    const int w   = t >> 6;
    const int l   = t & 63;
    const int lm  = l & 15;
    const int q   = l >> 4;

    const unsigned short* qF = wsu + QF_OFF + (size_t)db * 256 * 512;
    const unsigned short* kF = wsu + KF_OFF + (size_t)db * 256 * 512;

    const short8 qf0 = *reinterpret_cast<const short8*>(qF + (size_t)(nc0 * 2 + 0) * 512 + l * 8);
    const short8 qf1 = *reinterpret_cast<const short8*>(qF + (size_t)(nc0 * 2 + 1) * 512 + l * 8);

    const f32x4 zero = {0.f, 0.f, 0.f, 0.f};
    float za0[4] = {0.f, 0.f, 0.f, 0.f};
    float za1[4] = {0.f, 0.f, 0.f, 0.f};

    short8 kc_ = *reinterpret_cast<const short8*>(kF + (size_t)(w * 64) * 512 + l * 8);
    for (int it = 0; it < 64; it++) {
        const int nmt = w * 64 + ((it + 1) & 63);
        const short8 kn = *reinterpret_cast<const short8*>(kF + (size_t)nmt * 512 + l * 8);
        const f32x4 s0 = MFMA16(qf0, kc_, zero);
        const f32x4 s1 = MFMA16(qf1, kc_, zero);
#pragma unroll
        for (int r = 0; r < 4; r++) { za0[r] += EXP2F(s0[r]); za1[r] += EXP2F(s1[r]); }
        kc_ = kn;
    }

#pragma unroll
    for (int r = 0; r < 4; r++) {
        za0[r] += __shfl_xor(za0[r], 1); za0[r] += __shfl_xor(za0[r], 2);
        za0[r] += __shfl_xor(za0[r], 4); za0[r] += __shfl_xor(za0[r], 8);
        za1[r] += __shfl_xor(za1[r], 1); za1[r] += __shfl_xor(za1[r], 2);
        za1[r] += __shfl_xor(za1[r], 4); za1[r] += __shfl_xor(za1[r], 8);
    }

    __shared__ __align__(16) float zred[4][2][16];
    if (lm == 0) {
        *reinterpret_cast<float4*>(&zred[w][0][q * 4]) = float4{za0[0], za0[1], za0[2], za0[3]};
        *reinterpret_cast<float4*>(&zred[w][1][q * 4]) = float4{za1[0], za1[1], za1[2], za1[3]};
    }
    __syncthreads();
    if (t < 32) {
        const float Z = zred[0][t >> 4][t & 15] + zred[1][t >> 4][t & 15]
                      + zred[2][t >> 4][t & 15] + zred[3][t >> 4][t & 15];
        wsf[L2Z_OFFF + (size_t)db * N_ + nc0 * 32 + t] = -__log2f(Z);
    }
}

// ---------------------------------------------------------------------------
// Kernel 3: out = f + beta * V · E, E computed ONCE per (n,m).
// Block tile 256c x 64m (full C), BK=128 -> 32 ksteps, ONE barrier/kstep.
// 256 blocks x 512 threads (8 waves); wave w owns c-tiles w*2..w*2+1 (32c)
// and E-gen n-chunk w. ALL register buffers are named variables / constant-
// indexed arrays in an explicitly two-slot unrolled loop (R10/R11's runtime-
// indexed dbuf arrays caused 557MB of scratch spill - WRITE_SIZE evidence).
// Single A[8] (R8 schedule), q/z explicit dbuf. ~96 static VGPR/wave;
// __launch_bounds__(512,4) caps at 128 -> 2 blocks/CU (16 waves), no spill.
// XCD-pinned: xcd=id&7 -> db=xcd>>1; per-XCD hot set ~3MB < 4MB L2.
// ---------------------------------------------------------------------------
#define ESTR 136   // Es row stride (shorts): 68 dw == 4 mod 32 -> 2-way free

__global__ __launch_bounds__(512, 4) void attn_gemm(
    const float* __restrict__ fL, const float* __restrict__ fU,
    const float* __restrict__ betap,
    const unsigned short* __restrict__ wsu,
    const float* __restrict__ wsf,
    float* __restrict__ out)
{
    const int id  = blockIdx.x;
    const int xcd = id & 7;
    const int db  = xcd >> 1;
    const int mt  = (id >> 3) + ((xcd & 1) << 5);   // 0..63
    const int d   = db >> 1;
    const int b   = db & 1;
    const int t   = threadIdx.x;
    const int w   = t >> 6;          // 0..7
    const int l   = t & 63;
    const int lm  = l & 15;
    const int q   = l >> 4;
    const int m0  = mt * 64;

    const unsigned short* qF = wsu + QF_OFF + (size_t)db * 256 * 512;
    const unsigned short* kF = wsu + KF_OFF + (size_t)db * 256 * 512;
    const unsigned short* VF = wsu + VF_OFF + (size_t)db * 16 * 128 * 512;
    const float* l2z = wsf + L2Z_OFFF + (size_t)db * N_;
    const float* f = ((d == 0) ? fL : fU) + (size_t)b * C_ * N_;
    float*       o = out + (size_t)db * C_ * N_;

    __shared__ __align__(16) unsigned short Es[2][64 * ESTR];  // [m 64][n 128]

    // persistent k-frags: this block's 64 m (zero quads baked into kF)
    short8 kf2[4];
#pragma unroll
    for (int mb = 0; mb < 4; mb++)
        kf2[mb] = *reinterpret_cast<const short8*>(
            kF + (size_t)(mt * 4 + mb) * 512 + l * 8);

    // A-frag bases: wave w owns c-tiles w*2, w*2+1 (32 c)
    const unsigned short* Ab0 = VF + (size_t)(w * 2 + 0) * 128 * 512 + l * 8;
    const unsigned short* Ab1 = VF + (size_t)(w * 2 + 1) * 128 * 512 + l * 8;
    const unsigned short* qrow = qF + (size_t)w * 512 + l * 8;
    const float*          zrow = l2z + w * 16 + q * 4;

    f32x4 acc[2][4];
#pragma unroll
    for (int cb = 0; cb < 2; cb++)
#pragma unroll
        for (int mb = 0; mb < 4; mb++) acc[cb][mb] = f32x4{0.f, 0.f, 0.f, 0.f};

    short8 A[8];            // single buffer, constant-indexed only
    short8 qv0, qv1;
    f32x4  zv0, zv1;

    auto loadA = [&](int i) {
        const size_t nc = (size_t)((i & 31) * 4) * 512;
#pragma unroll
        for (int kc = 0; kc < 4; kc++) {
            A[kc]     = *reinterpret_cast<const short8*>(Ab0 + nc + (size_t)kc * 512);
            A[4 + kc] = *reinterpret_cast<const short8*>(Ab1 + nc + (size_t)kc * 512);
        }
    };
    auto egen = [&](const short8& qv_, const f32x4& zv_, unsigned short* Eb) {
#pragma unroll
        for (int mb = 0; mb < 4; mb++) {
            const f32x4 sv = MFMA16(qv_, kf2[mb], zv_);
            uint2 p;
            p.x = pk2(EXP2F(sv[0]), EXP2F(sv[1]));
            p.y = pk2(EXP2F(sv[2]), EXP2F(sv[3]));
            *reinterpret_cast<uint2*>(
                Eb + (mb * 16 + lm) * ESTR + w * 16 + q * 4) = p;
        }
    };
    auto mainm = [&](const unsigned short* Eb) {
#pragma unroll
        for (int kc = 0; kc < 4; kc++) {
            short8 Bf[4];
#pragma unroll
            for (int mb = 0; mb < 4; mb++)
                Bf[mb] = *reinterpret_cast<const short8*>(
                    Eb + (mb * 16 + lm) * ESTR + kc * 32 + q * 8);
#pragma unroll
            for (int mb = 0; mb < 4; mb++) {
                acc[0][mb] = MFMA16(A[kc],     Bf[mb], acc[0][mb]);
                acc[1][mb] = MFMA16(A[4 + kc], Bf[mb], acc[1][mb]);
            }
        }
    };

    loadA(0);
    qv0 = *reinterpret_cast<const short8*>(qrow);
    zv0 = *reinterpret_cast<const f32x4*>(zrow);
    qv1 = *reinterpret_cast<const short8*>(qrow + (size_t)(1 * 8) * 512);
    zv1 = *reinterpret_cast<const f32x4*>(zrow + 1 * 128);

    for (int i = 0; i < 32; i += 2) {
        // ---- slot 0: E(i), A(i) ----
        egen(qv0, zv0, Es[0]);
        __syncthreads();                 // Es[0] ready; drains A(i), QZ(i+1)
        {
            const int ii = (i + 2) & 31;
            qv0 = *reinterpret_cast<const short8*>(qrow + (size_t)(ii * 8) * 512);
            zv0 = *reinterpret_cast<const f32x4*>(zrow + ii * 128);
        }
        mainm(Es[0]);                    // consumes A(i)
        loadA(i + 1);                    // drained by next barrier

        // ---- slot 1: E(i+1), A(i+1) ----
        egen(qv1, zv1, Es[1]);
        __syncthreads();                 // Es[1] ready; drains A(i+1), QZ(i+2)
        {
            const int ii = (i + 3) & 31;
            qv1 = *reinterpret_cast<const short8*>(qrow + (size_t)(ii * 8) * 512);
            zv1 = *reinterpret_cast<const f32x4*>(zrow + ii * 128);
        }
        mainm(Es[1]);                    // consumes A(i+1)
        loadA(i + 2);
    }

    // epilogue: out = f + beta * acc  (D rows c = q*4+r, col m = lm)
    const float beta = *betap;
#pragma unroll
    for (int cb = 0; cb < 2; cb++) {
#pragma unroll
        for (int mb = 0; mb < 4; mb++) {
            const int c = w * 32 + cb * 16 + q * 4;
            const int m = m0 + mb * 16 + lm;
#pragma unroll
            for (int r = 0; r < 4; r++) {
                const size_t off = (size_t)(c + r) * N_ + m;
                o[off] = f[off] + beta * acc[cb][mb][r];
            }
        }
    }
}

// ---------------------------------------------------------------------------
extern "C" void kernel_launch(void* const* d_in, const int* in_sizes, int n_in,
                              void* d_out, int out_size, void* d_ws, size_t ws_size,
                              hipStream_t stream)
{
    const float* fL   = (const float*)d_in[0];
    const float* fU   = (const float*)d_in[1];
    const float* qL_w = (const float*)d_in[2];
    const float* qL_b = (const float*)d_in[3];
    const float* kU_w = (const float*)d_in[4];
    const float* kU_b = (const float*)d_in[5];
    const float* vU_w = (const float*)d_in[6];
    const float* vU_b = (const float*)d_in[7];
    const float* qU_w = (const float*)d_in[8];
    const float* qU_b = (const float*)d_in[9];
    const float* kL_w = (const float*)d_in[10];
    const float* kL_b = (const float*)d_in[11];
    const float* vL_w = (const float*)d_in[12];
    const float* vL_b = (const float*)d_in[13];
    const float* beta = (const float*)d_in[14];

    unsigned short* wsu  = (unsigned short*)d_ws;
    float*          wsf  = (float*)d_ws;
    float*          outf = (float*)d_out;

    fused_pre<<<dim3(128, 1, 4), 256, 0, stream>>>(
        fL, fU, qL_w, qL_b, kL_w, kL_b, vL_w, vL_b,
        qU_w, qU_b, kU_w, kU_b, vU_w, vU_b, wsu);

    zcalc<<<dim3(128, B_, 2), 256, 0, stream>>>(wsu, wsf);

    attn_gemm<<<dim3(256), 512, 0, stream>>>(
        fL, fU, beta, wsu, wsf, outf);
}